// Round 12
// baseline (2508.800 us; speedup 1.0000x reference)
//
#include <hip/hip_runtime.h>

#define SEQ 12

typedef __attribute__((ext_vector_type(8))) short bf16x8;   // 8 bf16 bit patterns (4 VGPRs)
typedef __attribute__((ext_vector_type(4))) float f32x4;
typedef __attribute__((ext_vector_type(4))) unsigned short us4;

__device__ __forceinline__ unsigned short f2bf(float x) {
    unsigned u = __builtin_bit_cast(unsigned, x);
    u += 0x7fffu + ((u >> 16) & 1u);            // round-to-nearest-even
    return (unsigned short)(u >> 16);
}
__device__ __forceinline__ float bf2f(unsigned short h) {
    unsigned u = ((unsigned)h) << 16;
    return __builtin_bit_cast(float, u);
}
// native-rate activations (r7): v_rcp_f32 + v_exp_f32, inf-safe at both tails.
__device__ __forceinline__ float sigf(float x) {
    return __builtin_amdgcn_rcpf(1.0f + __builtin_amdgcn_exp2f(-1.4426950408889634f * x));
}
__device__ __forceinline__ float tanhf_(float x) {
    return 1.0f - 2.0f * __builtin_amdgcn_rcpf(1.0f + __builtin_amdgcn_exp2f(2.8853900817779268f * x));
}

// ---------------- weight pack kernel (layout UNCHANGED) ----------------
// d_ws layout (ushort), SINGLE copy (640 KB):
//   [0,65536)        PRE0 = bf16(W_ih_l0[:, :128])  K=128   <- now read EVERY step (L0 x-part)
//   [65536,131072)   INIT = bf16(W_init [:, :128])  K=128
//   [131072,196608)   L0  = bf16(W_hh_l0)           K=128
//   [196608,327680)   L1  = bf16([W_ih_l1|W_hh_l1]) K=256
// fragment order: chunk = ((w*4+G)*KK + kk), within chunk: lane*8+j,
//   n = G*128 + w*16 + (lane&15),  k = kk*32 + (lane>>4)*8 + j
__global__ void pack_w(const float* __restrict__ Winit, const float* __restrict__ Wihl0,
                       const float* __restrict__ Whhl0, const float* __restrict__ Wihl1,
                       const float* __restrict__ Whhl1, unsigned short* __restrict__ pk,
                       int ncopy) {
    int id = blockIdx.x * 256 + threadIdx.x;
    if (id >= 327680) return;
    float v;
    if (id < 131072) {                       // PRE0 / INIT (stride 129, KK=4)
        int e = id & 65535;
        int c = e >> 9, r = e & 511;
        int lane = r >> 3, j = r & 7;
        int kk = c & 3, G = (c >> 2) & 3, w = c >> 4;
        int n = G * 128 + w * 16 + (lane & 15);
        int k = kk * 32 + (lane >> 4) * 8 + j;
        const float* W = (id >> 16) ? Winit : Wihl0;
        v = W[n * 129 + k];
    } else if (id < 196608) {                // L0 (stride 128, KK=4)
        int e = id - 131072;
        int c = e >> 9, r = e & 511;
        int lane = r >> 3, j = r & 7;
        int kk = c & 3, G = (c >> 2) & 3, w = c >> 4;
        int n = G * 128 + w * 16 + (lane & 15);
        int k = kk * 32 + (lane >> 4) * 8 + j;
        v = Whhl0[n * 128 + k];
    } else {                                 // L1 (K=256, KK=8)
        int e = id - 196608;
        int c = e >> 9, r = e & 511;
        int lane = r >> 3, j = r & 7;
        int kk = c & 7, G = (c >> 3) & 3, w = c >> 5;
        int n = G * 128 + w * 16 + (lane & 15);
        int k = kk * 32 + (lane >> 4) * 8 + j;
        v = (k < 128) ? Wihl1[n * 128 + k] : Whhl1[n * 128 + (k - 128)];
    }
    unsigned short hv = f2bf(v);
    for (int cpy = 0; cpy < ncopy; ++cpy) pk[cpy * 327680 + id] = hv;
}

// per-group helpers (macros so everything stays in registers, fully unrolled)
#define LOAD_A(hb, kkl) do { _Pragma("unroll") \
    for (int mt = 0; mt < 4; ++mt) \
        a[mt] = *(const bf16x8*)&(hb)[(mt * 16 + nq) * 128 + ((((kkl) * 4 + quad) ^ nq) << 3)]; \
    } while (0)
#define LOAD_B(slot, base, KK, kk) do { _Pragma("unroll") \
    for (int G = 0; G < 4; ++G) \
        bb[slot][G] = *(const bf16x8*)&(base)[((w * 4 + G) * (KK) + (kk)) * 512 + lane * 8]; \
    } while (0)
#define MFMA_G(slot) do { _Pragma("unroll") \
    for (int mt = 0; mt < 4; ++mt) { _Pragma("unroll") \
        for (int G = 0; G < 4; ++G) \
            acc[mt][G] = __builtin_amdgcn_mfma_f32_16x16x32_bf16(a[mt], bb[slot][G], acc[mt][G], 0, 0, 0); } \
    } while (0)

// ---------------- fused decoder kernel ----------------
// block: 512 thr (8 waves), Mt=64. wave w owns hidden cols [16w,16w+16) x 4 gates.
// Lineage: r6 weight prefetch ring; r7 native activations + distributed head;
// r9 single weight copy; r14 c-state bf16 idx-major LDS.
// r16: NO pre0. L0 is K=256 each step: acc init = bpre + iv*wcp (64 fma from
// 16 persistent ivv regs), then x-part (pkPRE, A from persistent s_x tile)
// kk0-3 + h-part (pkL0, A from h1) kk0-3. Rationale: allocator pins arch
// VGPRs at 128 in every observed variant (VGPR_Count=128, r7-r15) and spills
// whatever arch-class state doesn't fit, regardless of AGPR headroom; pre0
// forced 48-128 AGPRs + arch-side traffic around it. With pre0 gone, loop
// state = acc 64 AGPR + ~115 arch regs -> under the cap at last. Cost:
// 16 vs 12 MFMA groups/step (+33% at 15% util) re-reading the L2-resident
// pkPRE tile. Same MFMA fragments/order -> numerics within bf16 tolerance.
__global__ __launch_bounds__(512) __attribute__((amdgpu_waves_per_eu(2, 2)))
void traj_main(const float* __restrict__ fused, const float* __restrict__ intent,
               const float* __restrict__ binit,
               const float* __restrict__ Winit, const float* __restrict__ Wihl0,
               const float* __restrict__ bihl0, const float* __restrict__ bhhl0,
               const float* __restrict__ bihl1, const float* __restrict__ bhhl1,
               const float* __restrict__ Wout, const float* __restrict__ bout,
               const unsigned short* __restrict__ pk,
               float* __restrict__ out, int Bsz) {
    __shared__ __align__(16) unsigned short s_x[64 * 128];   // x-tile, persists all steps (16 KB)
    __shared__ __align__(16) unsigned char  s_u[16384];      // s_xi (phase A) union c1 (loop)
    unsigned short* s_xi = (unsigned short*)s_u;             // 64x128 bf16 init-x tile
    unsigned short* s_c1 = (unsigned short*)s_u;             // [4][512][4] bf16 c1
    __shared__ __align__(16) unsigned short s_c2[4 * 512 * 4];   // [4][512][4] bf16 c2 (16 KB)
    __shared__ __align__(16) unsigned short s_h1[2][64 * 128];   // h1 dbuf ([1] = c1 staging pre-loop)
    __shared__ __align__(16) unsigned short s_h2[2][64 * 128];   // h2 dbuf ([1] = c2 staging pre-loop)
    __shared__ float s_wo[256];                                  // W_out (2x128)
    __shared__ float s_out[64 * 24];                             // per-step outputs

    const int tid = threadIdx.x;
    const int lane = tid & 63;
    const int w = tid >> 6;          // wave 0..7
    const int nq = lane & 15;
    const int quad = lane >> 4;
    const int m0 = blockIdx.x * 64;
    const int Bh = Bsz >> 1;

    const unsigned short* pkPRE = pk;
    const unsigned short* pkINI = pk + 65536;
    const unsigned short* pkL0  = pk + 131072;
    const unsigned short* pkL1  = pk + 196608;

    if (tid < 256) s_wo[tid] = Wout[tid];
    const float bo2 = bout[(tid >> 2) & 1];    // head: oc = bit2 of tid

    // per-lane column constants (n = G*128 + 16w + nq)
    float bpre[4], bl1[4], wcp[4], wci[4], bini[4];
#pragma unroll
    for (int G = 0; G < 4; ++G) {
        int n = G * 128 + w * 16 + nq;
        bpre[G] = bihl0[n] + bhhl0[n];
        bl1[G]  = bihl1[n] + bhhl1[n];
        wcp[G]  = Wihl0[n * 129 + 128];    // intent column of W_ih_l0
        wci[G]  = Winit[n * 129 + 128];    // intent column of W_init
        bini[G] = binit[n];
    }
    // per-row intent values for L0 acc init (persist; ml = mt*16+quad*4+r)
    f32x4 ivv[4];
#pragma unroll
    for (int mt = 0; mt < 4; ++mt)
#pragma unroll
        for (int r = 0; r < 4; ++r)
            ivv[mt][r] = intent[m0 + mt * 16 + quad * 4 + r];

    // ---- stage tiles as bf16 (swizzled A-layout)
#pragma unroll
    for (int it = 0; it < 8; ++it) {
        int f = it * 512 + tid;
        int row = f >> 5, fc = f & 31;
        int g = (row < 64) ? (m0 + row)
                           : ((row < 96) ? ((m0 >> 1) + (row - 64))
                                         : (Bh + (m0 >> 1) + (row - 96)));
        f32x4 v = *(const f32x4*)(fused + g * 128 + fc * 4);
        us4 u;
#pragma unroll
        for (int j = 0; j < 4; ++j) u[j] = f2bf(v[j]);
        int m = row & 63;
        int cp = (fc >> 1) ^ (m & 15);
        unsigned short* buf = (row < 64) ? s_x : s_xi;
        *(us4*)&buf[m * 128 + cp * 8 + (fc & 1) * 4] = u;
    }
    __syncthreads();

    // ======== phase A: INIT only (peak 64 AGPR) ========
    {
        f32x4 acc2[4][4];
#pragma unroll
        for (int mt = 0; mt < 4; ++mt)
#pragma unroll
            for (int G = 0; G < 4; ++G)
                acc2[mt][G] = (f32x4){0.f, 0.f, 0.f, 0.f};
#pragma unroll
        for (int kk = 0; kk < 4; ++kk) {
            bf16x8 a2[4], b2[4];
#pragma unroll
            for (int mt = 0; mt < 4; ++mt)
                a2[mt] = *(const bf16x8*)&s_xi[(mt * 16 + nq) * 128 + (((kk * 4 + quad) ^ nq) << 3)];
#pragma unroll
            for (int G = 0; G < 4; ++G)
                b2[G] = *(const bf16x8*)&pkINI[((w * 4 + G) * 4 + kk) * 512 + lane * 8];
#pragma unroll
            for (int mt = 0; mt < 4; ++mt)
#pragma unroll
                for (int G = 0; G < 4; ++G)
                    acc2[mt][G] = __builtin_amdgcn_mfma_f32_16x16x32_bf16(a2[mt], b2[G], acc2[mt][G], 0, 0, 0);
        }
#pragma unroll
        for (int mt = 0; mt < 4; ++mt)
#pragma unroll
            for (int r = 0; r < 4; ++r) {
                int ml = mt * 16 + quad * 4 + r;
                int grow = (mt < 2) ? ((m0 >> 1) + ml) : (Bh + (m0 >> 1) + (ml - 32));
                float iv2 = intent[grow];
#pragma unroll
                for (int G = 0; G < 4; ++G)
                    acc2[mt][G][r] += bini[G] + iv2 * wci[G];
            }
        // unpack init (torch-faithful flat reshape of [B,2H]->(2,B,H)):
        // G0/G1 -> h (swizzled bf16, s_h*[0]); G2/G3 -> c (linear bf16 staging s_h*[1]).
        int kq = w * 16 + nq, kc = kq >> 3, klo = kq & 7;
#pragma unroll
        for (int mt = 0; mt < 4; ++mt)
#pragma unroll
            for (int r = 0; r < 4; ++r) {
                int ri = mt * 16 + quad * 4 + r;
                int layer = mt >> 1;
                int ril = ri & 31;
#pragma unroll
                for (int G = 0; G < 4; ++G) {
                    int ml = 2 * ril + (G & 1);
                    unsigned short hv = f2bf(acc2[mt][G][r]);
                    if (G < 2) {
                        unsigned short* hb = layer ? s_h2[0] : s_h1[0];
                        hb[ml * 128 + ((kc ^ (ml & 15)) << 3) + klo] = hv;
                    } else {
                        unsigned short* cb = layer ? s_h2[1] : s_h1[1];
                        cb[ml * 128 + kq] = hv;
                    }
                }
            }
    }   // acc2 dead here
    __syncthreads();   // s_xi reads done (s_u may become c1); staging visible

    // ---- c staging -> conflict-free idx-major loop layout
    {
        int kq = w * 16 + nq;
#pragma unroll
        for (int mt = 0; mt < 4; ++mt)
#pragma unroll
            for (int r = 0; r < 4; ++r) {
                int ml = mt * 16 + quad * 4 + r;
                s_c1[mt * 2048 + tid * 4 + r] = s_h1[1][ml * 128 + kq];
                s_c2[mt * 2048 + tid * 4 + r] = s_h2[1][ml * 128 + kq];
            }
    }
    __syncthreads();   // c copy done before step 0 overwrites s_h*[1]

    // ---- prefetch ring warm-up: first two weight groups of step 0 (x-part)
    bf16x8 bb[2][4];
    LOAD_B(0, pkPRE, 4, 0);
    LOAD_B(1, pkPRE, 4, 1);

    // ---- 12 decode steps; 16 groups/step: L0 = PRE kk0-3 (A=s_x) + L0 kk0-3
    // (A=h1), K=256; L1 = kk0-7 (A=h1_new|h2), K=256. Ring: MFMA(slot) then
    // refill same slot with the group 2 ahead.
#pragma unroll 1
    for (int s = 0; s < SEQ; ++s) {
        const int p = s & 1;
        const unsigned short* h1r = s_h1[p];
        unsigned short*       h1w = s_h1[1 - p];
        const unsigned short* h2r = s_h2[p];
        unsigned short*       h2w = s_h2[1 - p];

        f32x4 acc[4][4];
        bf16x8 a[4];
        // layer0: acc = (bpre + iv*wcp) + [x | h1] @ [Wihl0 | Whhl0]^T  (K=256)
#pragma unroll
        for (int mt = 0; mt < 4; ++mt)
#pragma unroll
            for (int G = 0; G < 4; ++G)
#pragma unroll
                for (int rr = 0; rr < 4; ++rr)
                    acc[mt][G][rr] = bpre[G] + ivv[mt][rr] * wcp[G];
        LOAD_A(s_x, 0); MFMA_G(0); LOAD_B(0, pkPRE, 4, 2);
        LOAD_A(s_x, 1); MFMA_G(1); LOAD_B(1, pkPRE, 4, 3);
        LOAD_A(s_x, 2); MFMA_G(0); LOAD_B(0, pkL0, 4, 0);
        LOAD_A(s_x, 3); MFMA_G(1); LOAD_B(1, pkL0, 4, 1);
        LOAD_A(h1r, 0); MFMA_G(0); LOAD_B(0, pkL0, 4, 2);
        LOAD_A(h1r, 1); MFMA_G(1); LOAD_B(1, pkL0, 4, 3);
        LOAD_A(h1r, 2); MFMA_G(0); LOAD_B(0, pkL1, 8, 0);
        LOAD_A(h1r, 3); MFMA_G(1); LOAD_B(1, pkL1, 8, 1);
        // pointwise layer0 (loads for L1 k0/k1 in flight, covered by this + barrier)
#pragma unroll
        for (int mt = 0; mt < 4; ++mt) {
            us4 ch = *(const us4*)&s_c1[mt * 2048 + tid * 4];
#pragma unroll
            for (int r = 0; r < 4; ++r) {
                float iv = acc[mt][0][r], fv = acc[mt][1][r], gv = acc[mt][2][r], ov = acc[mt][3][r];
                float cn = sigf(fv) * bf2f(ch[r]) + sigf(iv) * tanhf_(gv);
                float hn = sigf(ov) * tanhf_(cn);
                ch[r] = f2bf(cn);
                int ml = mt * 16 + quad * 4 + r;
                h1w[ml * 128 + ((((w * 2) + (nq >> 3)) ^ (quad * 4 + r)) << 3) + (nq & 7)] = f2bf(hn);
            }
            *(us4*)&s_c1[mt * 2048 + tid * 4] = ch;
        }
        __syncthreads();   // B1: new h1 visible
        // layer1: acc = bl1 + [h1_new | h2] @ [Wihl1 | Whhl1]^T  (K=256)
#pragma unroll
        for (int mt = 0; mt < 4; ++mt)
#pragma unroll
            for (int G = 0; G < 4; ++G)
                acc[mt][G] = (f32x4){bl1[G], bl1[G], bl1[G], bl1[G]};
        LOAD_A(h1w, 0); MFMA_G(0); LOAD_B(0, pkL1, 8, 2);
        LOAD_A(h1w, 1); MFMA_G(1); LOAD_B(1, pkL1, 8, 3);
        LOAD_A(h1w, 2); MFMA_G(0); LOAD_B(0, pkL1, 8, 4);
        LOAD_A(h1w, 3); MFMA_G(1); LOAD_B(1, pkL1, 8, 5);
        LOAD_A(h2r, 0); MFMA_G(0); LOAD_B(0, pkL1, 8, 6);
        LOAD_A(h2r, 1); MFMA_G(1); LOAD_B(1, pkL1, 8, 7);
        LOAD_A(h2r, 2); MFMA_G(0); LOAD_B(0, pkPRE, 4, 0);   // next step x-part k0
        LOAD_A(h2r, 3); MFMA_G(1); LOAD_B(1, pkPRE, 4, 1);   // next step x-part k1
        // pointwise layer1 (next-step loads in flight over pointwise+head+barrier)
#pragma unroll
        for (int mt = 0; mt < 4; ++mt) {
            us4 ch = *(const us4*)&s_c2[mt * 2048 + tid * 4];
#pragma unroll
            for (int r = 0; r < 4; ++r) {
                float iv = acc[mt][0][r], fv = acc[mt][1][r], gv = acc[mt][2][r], ov = acc[mt][3][r];
                float cn = sigf(fv) * bf2f(ch[r]) + sigf(iv) * tanhf_(gv);
                float hn = sigf(ov) * tanhf_(cn);
                ch[r] = f2bf(cn);
                int ml = mt * 16 + quad * 4 + r;
                h2w[ml * 128 + ((((w * 2) + (nq >> 3)) ^ (quad * 4 + r)) << 3) + (nq & 7)] = f2bf(hn);
            }
            *(us4*)&s_c2[mt * 2048 + tid * 4] = ch;
        }
        __syncthreads();   // B2: new h2 visible
        // output head: out[m, s, :] = h2_new @ Wout^T + bout, spread over all
        // 512 threads: tid -> (ml = tid>>3, oc = bit2, kc = bits[1:0] -> 4 of 16
        // column chunks each), then reduce the 4 partials with shfl_xor.
        {
            int ml = tid >> 3;
            int kc = tid & 3;
            const float* wr = s_wo + ((tid >> 2) & 1) * 128;
            int mx = ml & 15;
            float sum = 0.f;
#pragma unroll
            for (int c4 = 0; c4 < 4; ++c4) {
                int c = kc * 4 + c4;
                bf16x8 hv = *(const bf16x8*)&h2w[ml * 128 + ((c ^ mx) << 3)];
                int k0 = c << 3;
#pragma unroll
                for (int j = 0; j < 8; ++j)
                    sum += bf2f((unsigned short)hv[j]) * wr[k0 + j];
            }
            sum += __shfl_xor(sum, 1);
            sum += __shfl_xor(sum, 2);
            if (kc == 0) s_out[ml * 24 + s * 2 + ((tid >> 2) & 1)] = sum + bo2;
        }
    }
    __syncthreads();
    // single contiguous coalesced store: 64 samples x 24 floats = 6 KB
    for (int i = tid; i < 1536; i += 512) out[m0 * 24 + i] = s_out[i];
}

extern "C" void kernel_launch(void* const* d_in, const int* in_sizes, int n_in,
                              void* d_out, int out_size, void* d_ws, size_t ws_size,
                              hipStream_t stream) {
    const float* fused  = (const float*)d_in[0];
    const float* intent = (const float*)d_in[1];
    const float* Winit  = (const float*)d_in[2];
    const float* binit  = (const float*)d_in[3];
    const float* Wihl0  = (const float*)d_in[4];
    const float* Whhl0  = (const float*)d_in[5];
    const float* bihl0  = (const float*)d_in[6];
    const float* bhhl0  = (const float*)d_in[7];
    const float* Wihl1  = (const float*)d_in[8];
    const float* Whhl1  = (const float*)d_in[9];
    const float* bihl1  = (const float*)d_in[10];
    const float* bhhl1  = (const float*)d_in[11];
    const float* Wout   = (const float*)d_in[12];
    const float* bout   = (const float*)d_in[13];
    int Bsz = in_sizes[0] / 128;

    unsigned short* pkw = (unsigned short*)d_ws;   // single 640 KB copy
    pack_w<<<1280, 256, 0, stream>>>(Winit, Wihl0, Whhl0, Wihl1, Whhl1, pkw, 1);
    traj_main<<<Bsz / 64, 512, 0, stream>>>(fused, intent, binit, Winit, Wihl0, bihl0,
                                            bhhl0, bihl1, bhhl1, Wout, bout, pkw,
                                            (float*)d_out, Bsz);
}

// Round 13
// 1883.022 us; speedup vs baseline: 1.3323x; 1.3323x over previous
//
#include <hip/hip_runtime.h>

#define SEQ 12

typedef __attribute__((ext_vector_type(8))) short bf16x8;   // 8 bf16 bit patterns (4 VGPRs)
typedef __attribute__((ext_vector_type(4))) float f32x4;
typedef __attribute__((ext_vector_type(4))) unsigned short us4;

__device__ __forceinline__ unsigned short f2bf(float x) {
    unsigned u = __builtin_bit_cast(unsigned, x);
    u += 0x7fffu + ((u >> 16) & 1u);            // round-to-nearest-even
    return (unsigned short)(u >> 16);
}
__device__ __forceinline__ float bf2f(unsigned short h) {
    unsigned u = ((unsigned)h) << 16;
    return __builtin_bit_cast(float, u);
}
// native-rate activations (r7): v_rcp_f32 + v_exp_f32, inf-safe at both tails.
__device__ __forceinline__ float sigf(float x) {
    return __builtin_amdgcn_rcpf(1.0f + __builtin_amdgcn_exp2f(-1.4426950408889634f * x));
}
__device__ __forceinline__ float tanhf_(float x) {
    return 1.0f - 2.0f * __builtin_amdgcn_rcpf(1.0f + __builtin_amdgcn_exp2f(2.8853900817779268f * x));
}

// ---------------- weight pack kernel (layout UNCHANGED) ----------------
// d_ws layout (ushort), SINGLE copy (640 KB):
//   [0,65536)        PRE0 = bf16(W_ih_l0[:, :128])  K=128
//   [65536,131072)   INIT = bf16(W_init [:, :128])  K=128
//   [131072,196608)   L0  = bf16(W_hh_l0)           K=128
//   [196608,327680)   L1  = bf16([W_ih_l1|W_hh_l1]) K=256
// fragment order: chunk = ((w*4+G)*KK + kk), within chunk: lane*8+j,
//   n = G*128 + w*16 + (lane&15),  k = kk*32 + (lane>>4)*8 + j
__global__ void pack_w(const float* __restrict__ Winit, const float* __restrict__ Wihl0,
                       const float* __restrict__ Whhl0, const float* __restrict__ Wihl1,
                       const float* __restrict__ Whhl1, unsigned short* __restrict__ pk,
                       int ncopy) {
    int id = blockIdx.x * 256 + threadIdx.x;
    if (id >= 327680) return;
    float v;
    if (id < 131072) {                       // PRE0 / INIT (stride 129, KK=4)
        int e = id & 65535;
        int c = e >> 9, r = e & 511;
        int lane = r >> 3, j = r & 7;
        int kk = c & 3, G = (c >> 2) & 3, w = c >> 4;
        int n = G * 128 + w * 16 + (lane & 15);
        int k = kk * 32 + (lane >> 4) * 8 + j;
        const float* W = (id >> 16) ? Winit : Wihl0;
        v = W[n * 129 + k];
    } else if (id < 196608) {                // L0 (stride 128, KK=4)
        int e = id - 131072;
        int c = e >> 9, r = e & 511;
        int lane = r >> 3, j = r & 7;
        int kk = c & 3, G = (c >> 2) & 3, w = c >> 4;
        int n = G * 128 + w * 16 + (lane & 15);
        int k = kk * 32 + (lane >> 4) * 8 + j;
        v = Whhl0[n * 128 + k];
    } else {                                 // L1 (K=256, KK=8)
        int e = id - 196608;
        int c = e >> 9, r = e & 511;
        int lane = r >> 3, j = r & 7;
        int kk = c & 7, G = (c >> 3) & 3, w = c >> 5;
        int n = G * 128 + w * 16 + (lane & 15);
        int k = kk * 32 + (lane >> 4) * 8 + j;
        v = (k < 128) ? Wihl1[n * 128 + k] : Whhl1[n * 128 + (k - 128)];
    }
    unsigned short hv = f2bf(v);
    for (int cpy = 0; cpy < ncopy; ++cpy) pk[cpy * 327680 + id] = hv;
}

// per-group helpers (macros so everything stays in registers, fully unrolled)
#define LOAD_A(hb, kkl) do { _Pragma("unroll") \
    for (int mt = 0; mt < 4; ++mt) \
        a[mt] = *(const bf16x8*)&(hb)[(mt * 16 + nq) * 128 + ((((kkl) * 4 + quad) ^ nq) << 3)]; \
    } while (0)
#define LOAD_B(slot, base, KK, kk) do { _Pragma("unroll") \
    for (int G = 0; G < 4; ++G) \
        bb[slot][G] = *(const bf16x8*)&(base)[((w * 4 + G) * (KK) + (kk)) * 512 + lane * 8]; \
    } while (0)
#define MFMA_G(slot) do { _Pragma("unroll") \
    for (int mt = 0; mt < 4; ++mt) { _Pragma("unroll") \
        for (int G = 0; G < 4; ++G) \
            acc[mt][G] = __builtin_amdgcn_mfma_f32_16x16x32_bf16(a[mt], bb[slot][G], acc[mt][G], 0, 0, 0); } \
    } while (0)

// ---------------- fused decoder kernel ----------------
// block: 512 thr (8 waves), Mt=64. wave w owns hidden cols [16w,16w+16) x 4 gates.
// Lineage: r6 weight ring; r7 native activations + distributed head; r9 single
// weight copy; r14 two-pass phase A + c bf16 idx-major LDS + pre0 mt3 LDS (best,
// 1880us). r16 falsified the register-spill model for WRITE_SIZE; counters say
// the real limiter is weight-load LATENCY: ~40% of the 9.4 GB/dispatch weight
// stream misses L2 (streamed x + write churn evict it) and lands at L3/HBM
// (250-900 cy), while the 2-deep ring covers only ~160 cy of issue distance.
// r17: 3-DEEP B-RING (slot = group mod 3, refill 3 groups ahead) -> ~240+ cy
// coverage, and 3 (was 2) next-step L0 groups prefetched across the
// pointwise+head+barrier gap. Everything else identical to r14.
__global__ __launch_bounds__(512) __attribute__((amdgpu_waves_per_eu(2, 2)))
void traj_main(const float* __restrict__ fused, const float* __restrict__ intent,
               const float* __restrict__ binit,
               const float* __restrict__ Winit, const float* __restrict__ Wihl0,
               const float* __restrict__ bihl0, const float* __restrict__ bhhl0,
               const float* __restrict__ bihl1, const float* __restrict__ bhhl1,
               const float* __restrict__ Wout, const float* __restrict__ bout,
               const unsigned short* __restrict__ pk,
               float* __restrict__ out, int Bsz) {
    // phase-A x-tiles union c1+c2 loop storage (x dead after PRE0 pass)
    __shared__ __align__(16) unsigned char s_u[32768];
    unsigned short* s_x  = (unsigned short*)s_u;            // 64x128 bf16 (16 KB)
    unsigned short* s_xi = (unsigned short*)(s_u + 16384);  // 64x128 bf16 (16 KB)
    unsigned short* s_c1 = (unsigned short*)s_u;            // [4][512][4] bf16 (16 KB)
    unsigned short* s_c2 = (unsigned short*)(s_u + 16384);  // [4][512][4] bf16 (16 KB)
    __shared__ __align__(16) float s_pre[4 * 512 * 4];      // pre0 mt=3: [G][tid][r] f32 (32 KB)
    __shared__ __align__(16) unsigned short s_h1[2][64 * 128];   // h1 dbuf ([1] = c1 staging pre-loop)
    __shared__ __align__(16) unsigned short s_h2[2][64 * 128];   // h2 dbuf ([1] = c2 staging pre-loop)
    __shared__ float s_wo[256];                                  // W_out (2x128)
    __shared__ float s_out[64 * 24];                             // per-step outputs

    const int tid = threadIdx.x;
    const int lane = tid & 63;
    const int w = tid >> 6;          // wave 0..7
    const int nq = lane & 15;
    const int quad = lane >> 4;
    const int m0 = blockIdx.x * 64;
    const int Bh = Bsz >> 1;

    const unsigned short* pkPRE = pk;
    const unsigned short* pkINI = pk + 65536;
    const unsigned short* pkL0  = pk + 131072;
    const unsigned short* pkL1  = pk + 196608;

    if (tid < 256) s_wo[tid] = Wout[tid];
    const float bo2 = bout[(tid >> 2) & 1];    // head: oc = bit2 of tid

    // per-lane column constants (n = G*128 + 16w + nq)
    float bpre[4], bl1[4], wcp[4], wci[4], bini[4];
#pragma unroll
    for (int G = 0; G < 4; ++G) {
        int n = G * 128 + w * 16 + nq;
        bpre[G] = bihl0[n] + bhhl0[n];
        bl1[G]  = bihl1[n] + bhhl1[n];
        wcp[G]  = Wihl0[n * 129 + 128];    // intent column of W_ih_l0
        wci[G]  = Winit[n * 129 + 128];    // intent column of W_init
        bini[G] = binit[n];
    }

    // ---- stage tiles as bf16 (swizzled A-layout)
#pragma unroll
    for (int it = 0; it < 8; ++it) {
        int f = it * 512 + tid;
        int row = f >> 5, fc = f & 31;
        int g = (row < 64) ? (m0 + row)
                           : ((row < 96) ? ((m0 >> 1) + (row - 64))
                                         : (Bh + (m0 >> 1) + (row - 96)));
        f32x4 v = *(const f32x4*)(fused + g * 128 + fc * 4);
        us4 u;
#pragma unroll
        for (int j = 0; j < 4; ++j) u[j] = f2bf(v[j]);
        int m = row & 63;
        int cp = (fc >> 1) ^ (m & 15);
        unsigned short* buf = (row < 64) ? s_x : s_xi;
        *(us4*)&buf[m * 128 + cp * 8 + (fc & 1) * 4] = u;
    }
    __syncthreads();

    // ======== phase A pass 1: INIT only (peak 64 AGPR) ========
    {
        f32x4 acc2[4][4];
#pragma unroll
        for (int mt = 0; mt < 4; ++mt)
#pragma unroll
            for (int G = 0; G < 4; ++G)
                acc2[mt][G] = (f32x4){0.f, 0.f, 0.f, 0.f};
#pragma unroll
        for (int kk = 0; kk < 4; ++kk) {
            bf16x8 a2[4], b2[4];
#pragma unroll
            for (int mt = 0; mt < 4; ++mt)
                a2[mt] = *(const bf16x8*)&s_xi[(mt * 16 + nq) * 128 + (((kk * 4 + quad) ^ nq) << 3)];
#pragma unroll
            for (int G = 0; G < 4; ++G)
                b2[G] = *(const bf16x8*)&pkINI[((w * 4 + G) * 4 + kk) * 512 + lane * 8];
#pragma unroll
            for (int mt = 0; mt < 4; ++mt)
#pragma unroll
                for (int G = 0; G < 4; ++G)
                    acc2[mt][G] = __builtin_amdgcn_mfma_f32_16x16x32_bf16(a2[mt], b2[G], acc2[mt][G], 0, 0, 0);
        }
#pragma unroll
        for (int mt = 0; mt < 4; ++mt)
#pragma unroll
            for (int r = 0; r < 4; ++r) {
                int ml = mt * 16 + quad * 4 + r;
                int grow = (mt < 2) ? ((m0 >> 1) + ml) : (Bh + (m0 >> 1) + (ml - 32));
                float iv2 = intent[grow];
#pragma unroll
                for (int G = 0; G < 4; ++G)
                    acc2[mt][G][r] += bini[G] + iv2 * wci[G];
            }
        // unpack init (torch-faithful flat reshape of [B,2H]->(2,B,H)):
        // G0/G1 -> h (swizzled bf16, s_h*[0]); G2/G3 -> c (linear bf16 staging
        // in s_h*[1], copied to loop layout after the PRE0 pass).
        int kq = w * 16 + nq, kc = kq >> 3, klo = kq & 7;
#pragma unroll
        for (int mt = 0; mt < 4; ++mt)
#pragma unroll
            for (int r = 0; r < 4; ++r) {
                int ri = mt * 16 + quad * 4 + r;
                int layer = mt >> 1;
                int ril = ri & 31;
#pragma unroll
                for (int G = 0; G < 4; ++G) {
                    int ml = 2 * ril + (G & 1);
                    unsigned short hv = f2bf(acc2[mt][G][r]);
                    if (G < 2) {
                        unsigned short* hb = layer ? s_h2[0] : s_h1[0];
                        hb[ml * 128 + ((kc ^ (ml & 15)) << 3) + klo] = hv;
                    } else {
                        unsigned short* cb = layer ? s_h2[1] : s_h1[1];
                        cb[ml * 128 + kq] = hv;
                    }
                }
            }
    }   // acc2 dead here

    // ======== phase A pass 2: PRE0 (peak 64 AGPR, acc2 retired) ========
    f32x4 pre0[3][4], pre3[4];
#pragma unroll
    for (int G = 0; G < 4; ++G) {
        pre3[G] = (f32x4){0.f, 0.f, 0.f, 0.f};
#pragma unroll
        for (int mt = 0; mt < 3; ++mt)
            pre0[mt][G] = (f32x4){0.f, 0.f, 0.f, 0.f};
    }
#pragma unroll
    for (int kk = 0; kk < 4; ++kk) {
        bf16x8 av[4], bv[4];
#pragma unroll
        for (int mt = 0; mt < 4; ++mt)
            av[mt] = *(const bf16x8*)&s_x[(mt * 16 + nq) * 128 + (((kk * 4 + quad) ^ nq) << 3)];
#pragma unroll
        for (int G = 0; G < 4; ++G)
            bv[G] = *(const bf16x8*)&pkPRE[((w * 4 + G) * 4 + kk) * 512 + lane * 8];
#pragma unroll
        for (int mt = 0; mt < 4; ++mt)
#pragma unroll
            for (int G = 0; G < 4; ++G) {
                f32x4& pd = (mt < 3) ? pre0[mt][G] : pre3[G];
                pd = __builtin_amdgcn_mfma_f32_16x16x32_bf16(av[mt], bv[G], pd, 0, 0, 0);
            }
    }
#pragma unroll
    for (int mt = 0; mt < 4; ++mt)
#pragma unroll
        for (int r = 0; r < 4; ++r) {
            int ml = mt * 16 + quad * 4 + r;
            float iv = intent[m0 + ml];
#pragma unroll
            for (int G = 0; G < 4; ++G) {
                f32x4& pd = (mt < 3) ? pre0[mt][G] : pre3[G];
                pd[r] += bpre[G] + iv * wcp[G];
            }
        }
    __syncthreads();   // all s_x/s_xi reads done; unpack h/c writes visible

    // ---- pre3 -> LDS (f32 exact); c staging -> conflict-free loop layout
#pragma unroll
    for (int G = 0; G < 4; ++G)
        *(f32x4*)&s_pre[G * 2048 + tid * 4] = pre3[G];
    {
        int kq = w * 16 + nq;
#pragma unroll
        for (int mt = 0; mt < 4; ++mt)
#pragma unroll
            for (int r = 0; r < 4; ++r) {
                int ml = mt * 16 + quad * 4 + r;
                s_c1[mt * 2048 + tid * 4 + r] = s_h1[1][ml * 128 + kq];
                s_c2[mt * 2048 + tid * 4 + r] = s_h2[1][ml * 128 + kq];
            }
    }
    __syncthreads();   // c copy done before step 0 overwrites s_h*[1]

    // ---- prefetch ring warm-up: first three weight groups of step 0
    bf16x8 bb[3][4];
    LOAD_B(0, pkL0, 4, 0);
    LOAD_B(1, pkL0, 4, 1);
    LOAD_B(2, pkL0, 4, 2);

    // ---- 12 decode steps; 12 groups/step (L0 kk0-3, L1 kk0-7), slot = g mod 3,
    // refill slot with the group 3 ahead.
#pragma unroll 1
    for (int s = 0; s < SEQ; ++s) {
        const int p = s & 1;
        const unsigned short* h1r = s_h1[p];
        unsigned short*       h1w = s_h1[1 - p];
        const unsigned short* h2r = s_h2[p];
        unsigned short*       h2w = s_h2[1 - p];

        f32x4 acc[4][4];
        bf16x8 a[4];
        // layer0: acc = pre0 + h1 @ Whhl0^T (K=128); mt 0-2 from AGPR, mt3 from LDS
#pragma unroll
        for (int mt = 0; mt < 3; ++mt)
#pragma unroll
            for (int G = 0; G < 4; ++G) acc[mt][G] = pre0[mt][G];
#pragma unroll
        for (int G = 0; G < 4; ++G)
            acc[3][G] = *(const f32x4*)&s_pre[G * 2048 + tid * 4];
        LOAD_A(h1r, 0); MFMA_G(0); LOAD_B(0, pkL0, 4, 3);
        LOAD_A(h1r, 1); MFMA_G(1); LOAD_B(1, pkL1, 8, 0);
        LOAD_A(h1r, 2); MFMA_G(2); LOAD_B(2, pkL1, 8, 1);
        LOAD_A(h1r, 3); MFMA_G(0); LOAD_B(0, pkL1, 8, 2);
        // pointwise layer0 (L1 kk0-2 loads in flight over pointwise + barrier)
#pragma unroll
        for (int mt = 0; mt < 4; ++mt) {
            us4 ch = *(const us4*)&s_c1[mt * 2048 + tid * 4];
#pragma unroll
            for (int r = 0; r < 4; ++r) {
                float iv = acc[mt][0][r], fv = acc[mt][1][r], gv = acc[mt][2][r], ov = acc[mt][3][r];
                float cn = sigf(fv) * bf2f(ch[r]) + sigf(iv) * tanhf_(gv);
                float hn = sigf(ov) * tanhf_(cn);
                ch[r] = f2bf(cn);
                int ml = mt * 16 + quad * 4 + r;
                h1w[ml * 128 + ((((w * 2) + (nq >> 3)) ^ (quad * 4 + r)) << 3) + (nq & 7)] = f2bf(hn);
            }
            *(us4*)&s_c1[mt * 2048 + tid * 4] = ch;
        }
        __syncthreads();   // B1: new h1 visible
        // layer1: acc = bl1 + [h1_new | h2] @ [Wihl1 | Whhl1]^T  (K=256)
#pragma unroll
        for (int mt = 0; mt < 4; ++mt)
#pragma unroll
            for (int G = 0; G < 4; ++G)
                acc[mt][G] = (f32x4){bl1[G], bl1[G], bl1[G], bl1[G]};
        LOAD_A(h1w, 0); MFMA_G(1); LOAD_B(1, pkL1, 8, 3);
        LOAD_A(h1w, 1); MFMA_G(2); LOAD_B(2, pkL1, 8, 4);
        LOAD_A(h1w, 2); MFMA_G(0); LOAD_B(0, pkL1, 8, 5);
        LOAD_A(h1w, 3); MFMA_G(1); LOAD_B(1, pkL1, 8, 6);
        LOAD_A(h2r, 0); MFMA_G(2); LOAD_B(2, pkL1, 8, 7);
        LOAD_A(h2r, 1); MFMA_G(0); LOAD_B(0, pkL0, 4, 0);   // next step L0 kk0
        LOAD_A(h2r, 2); MFMA_G(1); LOAD_B(1, pkL0, 4, 1);   // next step L0 kk1
        LOAD_A(h2r, 3); MFMA_G(2); LOAD_B(2, pkL0, 4, 2);   // next step L0 kk2
        // pointwise layer1 (next-step L0 kk0-2 in flight over pointwise+head+barrier)
#pragma unroll
        for (int mt = 0; mt < 4; ++mt) {
            us4 ch = *(const us4*)&s_c2[mt * 2048 + tid * 4];
#pragma unroll
            for (int r = 0; r < 4; ++r) {
                float iv = acc[mt][0][r], fv = acc[mt][1][r], gv = acc[mt][2][r], ov = acc[mt][3][r];
                float cn = sigf(fv) * bf2f(ch[r]) + sigf(iv) * tanhf_(gv);
                float hn = sigf(ov) * tanhf_(cn);
                ch[r] = f2bf(cn);
                int ml = mt * 16 + quad * 4 + r;
                h2w[ml * 128 + ((((w * 2) + (nq >> 3)) ^ (quad * 4 + r)) << 3) + (nq & 7)] = f2bf(hn);
            }
            *(us4*)&s_c2[mt * 2048 + tid * 4] = ch;
        }
        __syncthreads();   // B2: new h2 visible
        // output head: out[m, s, :] = h2_new @ Wout^T + bout, spread over all
        // 512 threads: tid -> (ml = tid>>3, oc = bit2, kc = bits[1:0] -> 4 of 16
        // column chunks each), then reduce the 4 partials with shfl_xor.
        {
            int ml = tid >> 3;
            int kc = tid & 3;
            const float* wr = s_wo + ((tid >> 2) & 1) * 128;
            int mx = ml & 15;
            float sum = 0.f;
#pragma unroll
            for (int c4 = 0; c4 < 4; ++c4) {
                int c = kc * 4 + c4;
                bf16x8 hv = *(const bf16x8*)&h2w[ml * 128 + ((c ^ mx) << 3)];
                int k0 = c << 3;
#pragma unroll
                for (int j = 0; j < 8; ++j)
                    sum += bf2f((unsigned short)hv[j]) * wr[k0 + j];
            }
            sum += __shfl_xor(sum, 1);
            sum += __shfl_xor(sum, 2);
            if (kc == 0) s_out[ml * 24 + s * 2 + ((tid >> 2) & 1)] = sum + bo2;
        }
    }
    __syncthreads();
    // single contiguous coalesced store: 64 samples x 24 floats = 6 KB
    for (int i = tid; i < 1536; i += 512) out[m0 * 24 + i] = s_out[i];
}

extern "C" void kernel_launch(void* const* d_in, const int* in_sizes, int n_in,
                              void* d_out, int out_size, void* d_ws, size_t ws_size,
                              hipStream_t stream) {
    const float* fused  = (const float*)d_in[0];
    const float* intent = (const float*)d_in[1];
    const float* Winit  = (const float*)d_in[2];
    const float* binit  = (const float*)d_in[3];
    const float* Wihl0  = (const float*)d_in[4];
    const float* Whhl0  = (const float*)d_in[5];
    const float* bihl0  = (const float*)d_in[6];
    const float* bhhl0  = (const float*)d_in[7];
    const float* Wihl1  = (const float*)d_in[8];
    const float* Whhl1  = (const float*)d_in[9];
    const float* bihl1  = (const float*)d_in[10];
    const float* bhhl1  = (const float*)d_in[11];
    const float* Wout   = (const float*)d_in[12];
    const float* bout   = (const float*)d_in[13];
    int Bsz = in_sizes[0] / 128;

    unsigned short* pkw = (unsigned short*)d_ws;   // single 640 KB copy
    pack_w<<<1280, 256, 0, stream>>>(Winit, Wihl0, Whhl0, Wihl1, Whhl1, pkw, 1);
    traj_main<<<Bsz / 64, 512, 0, stream>>>(fused, intent, binit, Winit, Wihl0, bihl0,
                                            bhhl0, bihl1, bhhl1, Wout, bout, pkw,
                                            (float*)d_out, Bsz);
}